// Round 14
// baseline (320.361 us; speedup 1.0000x reference)
//
#include <hip/hip_runtime.h>
#include <hip/hip_bf16.h>

typedef __attribute__((ext_vector_type(8))) short short8v;
typedef __attribute__((ext_vector_type(4))) short short4v;
typedef __attribute__((ext_vector_type(4))) float f32x4;
typedef __attribute__((ext_vector_type(8))) float f32x8;
typedef __attribute__((ext_vector_type(16))) float f32x16;
typedef __attribute__((ext_vector_type(2))) unsigned int uint2v;
typedef __attribute__((ext_vector_type(4))) unsigned int uint4v;

#define LRELU(v) ((v) > 0.f ? (v) : 0.1f * (v))
#define MFMA16(a, b, c) __builtin_amdgcn_mfma_f32_16x16x32_bf16((a), (b), (c), 0, 0, 0)
#define MFMA32(a, b, c) __builtin_amdgcn_mfma_f32_32x32x16_bf16((a), (b), (c), 0, 0, 0)

__device__ inline unsigned short f2bf(float f) {
    unsigned u = __float_as_uint(f);
    u += 0x7FFF + ((u >> 16) & 1);          // RNE
    return (unsigned short)(u >> 16);
}
__device__ inline float bf2f(unsigned short h) {
    return __uint_as_float(((unsigned)h) << 16);
}
__device__ inline unsigned cvt_pk_bf16(float a, float b) {
    unsigned r;
    asm("v_cvt_pk_bf16_f32 %0, %1, %2" : "=v"(r) : "v"(a), "v"(b));
    return r;
}
// Split 8 fp32 into hi/lo bf16 planes in-registers (RNE, HW cvt_pk).
__device__ inline void split8(f32x8 v, short8v& hh, short8v& ll) {
    uint4v hu, lu;
    #pragma unroll
    for (int p = 0; p < 4; ++p) {
        float v0 = v[2 * p], v1 = v[2 * p + 1];
        unsigned hp = cvt_pk_bf16(v0, v1);
        float h0 = __uint_as_float(hp << 16);
        float h1 = __uint_as_float(hp & 0xFFFF0000u);
        unsigned lp = cvt_pk_bf16(v0 - h0, v1 - h1);
        hu[p] = hp; lu[p] = lp;
    }
    hh = __builtin_bit_cast(short8v, hu);
    ll = __builtin_bit_cast(short8v, lu);
}

// ---------------------------------------------------------------------------
// Prep: repack CONV weights only into hi/lo bf16 fragments (123K elems).
// ---------------------------------------------------------------------------
__global__ __launch_bounds__(256) void prep_weights(
    const float* __restrict__ w2, const float* __restrict__ w3,
    short* __restrict__ Wf2h, short* __restrict__ Wf2l,
    short* __restrict__ Wq3h, short* __restrict__ Wq3l)
{
    const int N1 = 24576, N2 = 98304;
    int gid = blockIdx.x * 256 + threadIdx.x;
    if (gid >= N1 + N2) return;
    float v; short *ph, *pl; int o;
    if (gid < N1) {
        o = gid;
        int ii = o & 7, q = o >> 3;
        int lane = q & 63, q2 = q >> 6;
        int kf = q2 % 6, ctile = q2 / 6;
        int co = ctile * 16 + (lane & 15);
        int Kidx = kf * 32 + (lane >> 4) * 8 + ii;
        v = w2[(co * 64 + (Kidx & 63)) * 3 + (Kidx >> 6)];
        ph = Wf2h; pl = Wf2l;
    } else {
        o = gid - N1;
        int ii = o & 7, q = o >> 3;
        int lane = q & 63, q2 = q >> 6;
        int kstep = q2 % 24, ctile = q2 / 24;
        int co = ctile * 32 + (lane & 31);
        int Kidx = kstep * 16 + (lane >> 5) * 8 + ii;
        v = w3[(co * 128 + (Kidx & 127)) * 3 + (Kidx >> 7)];
        ph = Wq3h; pl = Wq3l;
    }
    unsigned short h = f2bf(v);
    ph[o] = (short)h;
    pl[o] = (short)f2bf(v - bf2f(h));
}

// ---------------------------------------------------------------------------
// Fused conv1(VALU fp32) + conv2 (16x16 MFMA) + conv3 (32x32 MFMA) + pools.
// 512 threads / 8 waves per block, one block per sequence.
// conv3 runs as TWO sequential t-half passes so only 32 AGPR of accumulator
// are live at once -> combined regs/wave <= 85 -> 6 waves/SIMD (3 blocks/CU).
// (r9's spill disaster was launch_bounds(512,6) with 64 live AGPR; the cap is
// feasible now that acc is halved. Spill sentinel: WRITE_SIZE must stay ~6.6MB.)
// ---------------------------------------------------------------------------
__global__ __launch_bounds__(512, 6) void conv_fused_mfma(
    const float* __restrict__ xg, const float* __restrict__ w1,
    const float* __restrict__ b1, const float* __restrict__ g1, const float* __restrict__ be1,
    const float* __restrict__ m1, const float* __restrict__ v1,
    const float* __restrict__ b2, const float* __restrict__ g2, const float* __restrict__ be2,
    const float* __restrict__ m2, const float* __restrict__ v2,
    const float* __restrict__ b3, const float* __restrict__ g3, const float* __restrict__ be3,
    const float* __restrict__ m3, const float* __restrict__ v3,
    const short* __restrict__ Wf2h, const short* __restrict__ Wf2l,
    const short* __restrict__ Wq3h, const short* __restrict__ Wq3l,
    short* __restrict__ ms)
{
    __shared__ float sx[6][130];                    // col t+1 holds time t
    __shared__ __align__(16) short h1s[130 * 64];   // [row=t+1][ci], swizzled
    __shared__ __align__(16) short h2s[130 * 128];  // [row=t+1][ci], swizzled

    const int tid = threadIdx.x;
    const int n = blockIdx.x;
    const int wv = tid >> 6, lane = tid & 63;
    const int l15 = lane & 15, lhi = lane >> 4;

    const float* xrow = xg + (size_t)n * 768;
    {
        int idx = tid;
        float vv = xrow[idx];
        int t = idx / 6, c = idx - t * 6;
        sx[c][t + 1] = vv;
        idx = tid + 512;
        if (idx < 768) {
            vv = xrow[idx];
            t = idx / 6; c = idx - t * 6;
            sx[c][t + 1] = vv;
        }
    }
    if (tid < 6)   { sx[tid][0] = 0.f; sx[tid][129] = 0.f; }
    if (tid < 64)  { h1s[tid] = 0; h1s[129 * 64 + tid] = 0; }
    if (tid < 128) { h2s[tid] = 0; h2s[129 * 128 + tid] = 0; }
    __syncthreads();

    // ---- conv1: 6 -> 64, fp32 VALU; thread = 4co x 4t (co across lanes) ----
    {
        const int t0 = (tid >> 4) * 4, co0 = (tid & 15) * 4;
        float a1v[4], c1v[4];
        #pragma unroll
        for (int c = 0; c < 4; ++c) {
            int co = co0 + c;
            float a = g1[co] * rsqrtf(v1[co] + 1e-5f);
            a1v[c] = a;
            c1v[c] = (b1[co] - m1[co]) * a + be1[co];
        }
        float acc[4][4];
        #pragma unroll
        for (int c = 0; c < 4; ++c)
            #pragma unroll
            for (int t = 0; t < 4; ++t) acc[c][t] = 0.f;
        #pragma unroll
        for (int ci = 0; ci < 6; ++ci) {
            float s[6];
            #pragma unroll
            for (int u = 0; u < 6; ++u) s[u] = sx[ci][t0 + u];
            #pragma unroll
            for (int c = 0; c < 4; ++c) {
                const float* wp = w1 + ((co0 + c) * 6 + ci) * 3;
                float wa = wp[0], wb = wp[1], wc = wp[2];
                #pragma unroll
                for (int t = 0; t < 4; ++t)
                    acc[c][t] = fmaf(wa, s[t], fmaf(wb, s[t + 1], fmaf(wc, s[t + 2], acc[c][t])));
            }
        }
        char* h1b = (char*)h1s;
        #pragma unroll
        for (int t = 0; t < 4; ++t) {
            short4v pk;
            #pragma unroll
            for (int c = 0; c < 4; ++c) {
                float v = fmaf(a1v[c], acc[c][t], c1v[c]);
                v = LRELU(v);
                pk[c] = (short)f2bf(v);
            }
            int row = t0 + t + 1;
            int byt = (row * 128 + co0 * 2) ^ ((row & 7) << 4);
            *(short4v*)(h1b + byt) = pk;
        }
    }
    __syncthreads();

    // ---- conv2: 64 -> 128 MFMA 16x16 (A=weights: D row=co, col=t) ----
    {
        f32x4 acc[8];
        #pragma unroll
        for (int j = 0; j < 8; ++j) acc[j] = (f32x4){0.f, 0.f, 0.f, 0.f};
        const char* h1b = (const char*)h1s;
        __builtin_amdgcn_s_setprio(1);
        for (int kf = 0; kf < 6; ++kf) {
            int k = kf >> 1, ci0 = (kf & 1) * 32;
            int colb = (ci0 + lhi * 8) * 2;
            size_t woff = ((size_t)(wv * 6 + kf) * 64 + lane) * 8;
            short8v ah = *(const short8v*)(Wf2h + woff);
            short8v al = *(const short8v*)(Wf2l + woff);
            #pragma unroll
            for (int j = 0; j < 8; ++j) {
                int row = j * 16 + l15 + k;
                short8v bfr = *(const short8v*)(h1b + ((row * 128 + colb) ^ ((row & 7) << 4)));
                acc[j] = MFMA16(ah, bfr, acc[j]);
                acc[j] = MFMA16(al, bfr, acc[j]);
            }
        }
        __builtin_amdgcn_s_setprio(0);
        char* h2b = (char*)h2s;
        {
            int cob = wv * 16 + lhi * 4;
            float a2v[4], c2v[4];
            #pragma unroll
            for (int c = 0; c < 4; ++c) {
                int co = cob + c;
                float a = g2[co] * rsqrtf(v2[co] + 1e-5f);
                a2v[c] = a;
                c2v[c] = (b2[co] - m2[co]) * a + be2[co];
            }
            #pragma unroll
            for (int j = 0; j < 8; ++j) {
                int t = j * 16 + l15;
                float v0 = fmaf(a2v[0], acc[j][0], c2v[0]); v0 = LRELU(v0);
                float v1_ = fmaf(a2v[1], acc[j][1], c2v[1]); v1_ = LRELU(v1_);
                float v2_ = fmaf(a2v[2], acc[j][2], c2v[2]); v2_ = LRELU(v2_);
                float v3_ = fmaf(a2v[3], acc[j][3], c2v[3]); v3_ = LRELU(v3_);
                short4v pk;
                pk[0] = (short)f2bf(v0); pk[1] = (short)f2bf(v1_);
                pk[2] = (short)f2bf(v2_); pk[3] = (short)f2bf(v3_);
                int row = t + 1;
                int byt = (row * 256 + cob * 2) ^ ((row & 7) << 4);
                *(short4v*)(h2b + byt) = pk;
            }
        }
    }
    __syncthreads();

    // ---- conv3: 128 -> 256 MFMA 32x32 swapped, TWO t-half passes + pools ----
    // Per pass only acc0/acc1 (32 AGPR) live. Weights re-read (L2-hot, cheap).
    {
        const int l31 = lane & 31, lh = lane >> 5;
        const char* h2b = (const char*)h2s;
        short* msrow = ms + (size_t)n * 3328;
        int co = wv * 32 + l31;
        float a3v = g3[co] * rsqrtf(v3[co] + 1e-5f);
        float c3v = (b3[co] - m3[co]) * a3v + be3[co];
        float h128 = 0.f;
        #pragma unroll 1
        for (int th = 0; th < 2; ++th) {
            f32x16 acc0, acc1;
            #pragma unroll
            for (int r = 0; r < 16; ++r) { acc0[r] = 0.f; acc1[r] = 0.f; }
            __builtin_amdgcn_s_setprio(1);
            for (int kstep = 0; kstep < 24; ++kstep) {
                int k = kstep >> 3;                         // conv tap 0..2
                int colb = (kstep & 7) * 32 + lh * 16;      // byte col of 8 ci
                size_t foff = ((size_t)(wv * 24 + kstep) * 64 + lane) * 8;
                short8v bh = *(const short8v*)(Wq3h + foff);
                short8v bl = *(const short8v*)(Wq3l + foff);
                int row0 = th * 64 + l31 + k;
                short8v afr0 = *(const short8v*)(h2b + ((row0 * 256 + colb) ^ ((row0 & 7) << 4)));
                acc0 = MFMA32(afr0, bh, acc0);
                acc0 = MFMA32(afr0, bl, acc0);
                int row1 = row0 + 32;
                short8v afr1 = *(const short8v*)(h2b + ((row1 * 256 + colb) ^ ((row1 & 7) << 4)));
                acc1 = MFMA32(afr1, bh, acc1);
                acc1 = MFMA32(afr1, bl, acc1);
            }
            __builtin_amdgcn_s_setprio(0);
            // pools for this t-half: acc0 -> bins th*4+{0,1}, acc1 -> th*4+{2,3}
            #pragma unroll
            for (int tt = 0; tt < 2; ++tt) {
                float b0 = 0.f, b1 = 0.f;
                #pragma unroll
                for (int r = 0; r < 8; ++r) {
                    float v = fmaf(a3v, tt ? acc1[r] : acc0[r], c3v);
                    v = LRELU(v);
                    b0 += v;
                }
                #pragma unroll
                for (int r = 8; r < 16; ++r) {
                    float v = fmaf(a3v, tt ? acc1[r] : acc0[r], c3v);
                    v = LRELU(v);
                    b1 += v;
                }
                b0 += __shfl_xor(b0, 32);
                b1 += __shfl_xor(b1, 32);
                if (lane < 32) {
                    unsigned pk = ((unsigned)f2bf(b1 * (1.f / 16.f)) << 16)
                                |  (unsigned)f2bf(b0 * (1.f / 16.f));
                    *(unsigned*)(msrow + co * 8 + th * 4 + tt * 2) = pk;
                    msrow[2048 + co * 4 + th * 2 + tt] = (short)f2bf((b0 + b1) * (1.f / 32.f));
                }
                h128 += b0 + b1;
            }
        }
        if (lane < 32) {
            msrow[3072 + co] = (short)f2bf(h128 * (1.f / 128.f));
        }
    }
}

// ---------------------------------------------------------------------------
// gemm1 split-K: P[kk][1024][512] f32 partials, no bias/act.
// W is fp32, split hi/lo IN-KERNEL (same bytes as pre-split bf16 planes).
// 256 threads; block 64n x 64m, 4 waves of 32n x 32m, K chunk = 832.
// ---------------------------------------------------------------------------
__global__ __launch_bounds__(256) void gemm1_splitk(
    const float* __restrict__ W, const short* __restrict__ Act,
    float* __restrict__ P)
{
    const int K = 3328, KCHUNK = 832;
    const int tid = threadIdx.x;
    const int w = tid >> 6, lane = tid & 63;
    const int l15 = lane & 15, lhi = lane >> 4;
    const int n0 = blockIdx.x * 64 + (w & 1) * 32;
    const int m0 = blockIdx.y * 64 + (w >> 1) * 32;
    const int kbeg = blockIdx.z * KCHUNK;

    f32x4 acc[2][2];
    #pragma unroll
    for (int i = 0; i < 2; ++i)
        #pragma unroll
        for (int j = 0; j < 2; ++j) acc[i][j] = (f32x4){0.f, 0.f, 0.f, 0.f};

    const float* wp0 = W + (size_t)(n0 + l15) * K + kbeg + lhi * 8;
    const float* wp1 = wp0 + 16 * K;
    const short* bp0 = Act + (size_t)(m0 + l15) * K + kbeg + lhi * 8;
    const short* bp1 = bp0 + 16 * K;

    #pragma unroll 2
    for (int k0 = 0; k0 < KCHUNK; k0 += 32) {
        short8v b0 = *(const short8v*)(bp0 + k0);
        short8v b1 = *(const short8v*)(bp1 + k0);
        f32x8 w0 = *(const f32x8*)(wp0 + k0);
        f32x8 w1 = *(const f32x8*)(wp1 + k0);
        short8v a0h, a0l, a1h, a1l;
        split8(w0, a0h, a0l);
        split8(w1, a1h, a1l);
        acc[0][0] = MFMA16(a0h, b0, acc[0][0]); acc[0][0] = MFMA16(a0l, b0, acc[0][0]);
        acc[0][1] = MFMA16(a0h, b1, acc[0][1]); acc[0][1] = MFMA16(a0l, b1, acc[0][1]);
        acc[1][0] = MFMA16(a1h, b0, acc[1][0]); acc[1][0] = MFMA16(a1l, b0, acc[1][0]);
        acc[1][1] = MFMA16(a1h, b1, acc[1][1]); acc[1][1] = MFMA16(a1l, b1, acc[1][1]);
    }

    float* Pk = P + (size_t)blockIdx.z * (1024 * 512);
    #pragma unroll
    for (int ni = 0; ni < 2; ++ni) {
        int nb = n0 + ni * 16 + lhi * 4;
        #pragma unroll
        for (int mi = 0; mi < 2; ++mi) {
            int m = m0 + mi * 16 + l15;
            *(f32x4*)(Pk + (size_t)m * 512 + nb) = acc[ni][mi];
        }
    }
}

// Combine split-K partials: sum 4 planes + bias + relu -> bf16 h2l.
__global__ __launch_bounds__(256) void combine_h2(
    const float* __restrict__ P, const float* __restrict__ bias,
    short* __restrict__ h2l)
{
    int i4 = blockIdx.x * 256 + threadIdx.x;     // 0..131071, 4 floats each
    const f32x4* p = (const f32x4*)P;
    f32x4 s0 = p[i4], s1 = p[i4 + 131072], s2 = p[i4 + 262144], s3 = p[i4 + 393216];
    int nb = (i4 * 4) & 511;
    f32x4 b = *(const f32x4*)(bias + nb);
    float v0 = fmaxf(s0[0] + s1[0] + s2[0] + s3[0] + b[0], 0.f);
    float v1 = fmaxf(s0[1] + s1[1] + s2[1] + s3[1] + b[1], 0.f);
    float v2 = fmaxf(s0[2] + s1[2] + s2[2] + s3[2] + b[2], 0.f);
    float v3 = fmaxf(s0[3] + s1[3] + s2[3] + s3[3] + b[3], 0.f);
    uint2v pk;
    pk[0] = cvt_pk_bf16(v0, v1);
    pk[1] = cvt_pk_bf16(v2, v3);
    *(uint2v*)(h2l + (size_t)i4 * 4) = pk;
}

// ---------------------------------------------------------------------------
// gemm2: out[1024][256] f32 = h2l[1024][512] x lw2^T + lb2.
// W fp32, split in-kernel. Block 32n x 32m, 4 waves of 16n x 16m. 256 blocks.
// ---------------------------------------------------------------------------
__global__ __launch_bounds__(256) void gemm2_kernel(
    const float* __restrict__ W, const short* __restrict__ Act,
    const float* __restrict__ bias, float* __restrict__ out)
{
    const int K = 512;
    const int tid = threadIdx.x;
    const int w = tid >> 6, lane = tid & 63;
    const int l15 = lane & 15, lhi = lane >> 4;
    const int n0 = blockIdx.x * 32 + (w & 1) * 16;
    const int m0 = blockIdx.y * 32 + (w >> 1) * 16;

    f32x4 acc = (f32x4){0.f, 0.f, 0.f, 0.f};
    const float* wp = W + (size_t)(n0 + l15) * K + lhi * 8;
    const short* bp = Act + (size_t)(m0 + l15) * K + lhi * 8;

    #pragma unroll 4
    for (int k0 = 0; k0 < K; k0 += 32) {
        short8v b = *(const short8v*)(bp + k0);
        f32x8 wv8 = *(const f32x8*)(wp + k0);
        short8v ah, al;
        split8(wv8, ah, al);
        acc = MFMA16(ah, b, acc);
        acc = MFMA16(al, b, acc);
    }

    f32x4 bs = *(const f32x4*)(bias + n0 + lhi * 4);
    f32x4 vv;
    #pragma unroll
    for (int r = 0; r < 4; ++r) vv[r] = acc[r] + bs[r];
    *(f32x4*)(out + (size_t)(m0 + l15) * 256 + n0 + lhi * 4) = vv;
}

extern "C" void kernel_launch(void* const* d_in, const int* in_sizes, int n_in,
                              void* d_out, int out_size, void* d_ws, size_t ws_size,
                              hipStream_t stream) {
    int I_x, I_w1, I_b1, I_w2, I_b2, I_w3, I_b3;
    int I_g1, I_be1, I_m1, I_v1, I_g2, I_be2, I_m2, I_v2, I_g3, I_be3, I_m3, I_v3;
    int I_lw1, I_lb1, I_lw2, I_lb2;
    if (in_sizes[3] == 24576) {
        I_x=0; I_w1=1; I_b1=2; I_w2=3; I_b2=4; I_w3=5; I_b3=6;
        I_g1=7; I_be1=8; I_m1=9; I_v1=10; I_g2=11; I_be2=12; I_m2=13; I_v2=14;
        I_g3=15; I_be3=16; I_m3=17; I_v3=18; I_lw1=19; I_lb1=20; I_lw2=21; I_lb2=22;
    } else {
        I_x=0; I_w1=1; I_b1=2; I_g1=3; I_be1=4; I_m1=5; I_v1=6;
        I_w2=7; I_b2=8; I_g2=9; I_be2=10; I_m2=11; I_v2=12;
        I_w3=13; I_b3=14; I_g3=15; I_be3=16; I_m3=17; I_v3=18;
        I_lw1=19; I_lb1=20; I_lw2=21; I_lb2=22;
    }

    const float* x   = (const float*)d_in[I_x];
    const float* w1  = (const float*)d_in[I_w1];
    const float* b1  = (const float*)d_in[I_b1];
    const float* w2  = (const float*)d_in[I_w2];
    const float* b2  = (const float*)d_in[I_b2];
    const float* w3  = (const float*)d_in[I_w3];
    const float* b3  = (const float*)d_in[I_b3];
    const float* g1  = (const float*)d_in[I_g1];
    const float* be1 = (const float*)d_in[I_be1];
    const float* m1  = (const float*)d_in[I_m1];
    const float* v1  = (const float*)d_in[I_v1];
    const float* g2  = (const float*)d_in[I_g2];
    const float* be2 = (const float*)d_in[I_be2];
    const float* m2  = (const float*)d_in[I_m2];
    const float* v2  = (const float*)d_in[I_v2];
    const float* g3  = (const float*)d_in[I_g3];
    const float* be3 = (const float*)d_in[I_be3];
    const float* m3  = (const float*)d_in[I_m3];
    const float* v3  = (const float*)d_in[I_v3];
    const float* lw1 = (const float*)d_in[I_lw1];
    const float* lb1 = (const float*)d_in[I_lb1];
    const float* lw2 = (const float*)d_in[I_lw2];
    const float* lb2 = (const float*)d_in[I_lb2];

    char* wsb = (char*)d_ws;
    short* ms   = (short*)(wsb);                 // 1024*3328*2 = 6,815,744
    short* h2l  = (short*)(wsb + 6815744);       // 1024*512*2  = 1,048,576
    short* Wf2h = (short*)(wsb + 7864320);       // 24576*2 = 49,152
    short* Wf2l = (short*)(wsb + 7913472);
    short* Wq3h = (short*)(wsb + 7962624);       // 98304*2 = 196,608
    short* Wq3l = (short*)(wsb + 8159232);       // -> 8,355,840
    float* P    = (float*)(wsb + 8355840);       // 4*1024*512*4 = 8,388,608 -> 16,744,448

    prep_weights<<<480, 256, 0, stream>>>(w2, w3, Wf2h, Wf2l, Wq3h, Wq3l);

    conv_fused_mfma<<<1024, 512, 0, stream>>>(
        x, w1, b1, g1, be1, m1, v1, b2, g2, be2, m2, v2,
        b3, g3, be3, m3, v3, Wf2h, Wf2l, Wq3h, Wq3l, ms);

    gemm1_splitk<<<dim3(8, 16, 4), 256, 0, stream>>>(lw1, ms, P);
    combine_h2<<<512, 256, 0, stream>>>(P, lb1, h2l);
    gemm2_kernel<<<dim3(8, 32), 256, 0, stream>>>(lw2, h2l, lb2, (float*)d_out);
}

// Round 15
// 120.513 us; speedup vs baseline: 2.6583x; 2.6583x over previous
//
#include <hip/hip_runtime.h>
#include <hip/hip_bf16.h>

typedef __attribute__((ext_vector_type(8))) short short8v;
typedef __attribute__((ext_vector_type(4))) short short4v;
typedef __attribute__((ext_vector_type(4))) float f32x4;
typedef __attribute__((ext_vector_type(8))) float f32x8;
typedef __attribute__((ext_vector_type(16))) float f32x16;
typedef __attribute__((ext_vector_type(2))) unsigned int uint2v;
typedef __attribute__((ext_vector_type(4))) unsigned int uint4v;

#define LRELU(v) ((v) > 0.f ? (v) : 0.1f * (v))
#define MFMA16(a, b, c) __builtin_amdgcn_mfma_f32_16x16x32_bf16((a), (b), (c), 0, 0, 0)
#define MFMA32(a, b, c) __builtin_amdgcn_mfma_f32_32x32x16_bf16((a), (b), (c), 0, 0, 0)

__device__ inline unsigned short f2bf(float f) {
    unsigned u = __float_as_uint(f);
    u += 0x7FFF + ((u >> 16) & 1);          // RNE
    return (unsigned short)(u >> 16);
}
__device__ inline float bf2f(unsigned short h) {
    return __uint_as_float(((unsigned)h) << 16);
}
__device__ inline unsigned cvt_pk_bf16(float a, float b) {
    unsigned r;
    asm("v_cvt_pk_bf16_f32 %0, %1, %2" : "=v"(r) : "v"(a), "v"(b));
    return r;
}
// Split 8 fp32 into hi/lo bf16 planes in-registers (RNE, HW cvt_pk).
__device__ inline void split8(f32x8 v, short8v& hh, short8v& ll) {
    uint4v hu, lu;
    #pragma unroll
    for (int p = 0; p < 4; ++p) {
        float v0 = v[2 * p], v1 = v[2 * p + 1];
        unsigned hp = cvt_pk_bf16(v0, v1);
        float h0 = __uint_as_float(hp << 16);
        float h1 = __uint_as_float(hp & 0xFFFF0000u);
        unsigned lp = cvt_pk_bf16(v0 - h0, v1 - h1);
        hu[p] = hp; lu[p] = lp;
    }
    hh = __builtin_bit_cast(short8v, hu);
    ll = __builtin_bit_cast(short8v, lu);
}

// ---------------------------------------------------------------------------
// Prep: repack CONV weights only into hi/lo bf16 fragments (123K elems).
// lw1/lw2 stay fp32 — the GEMMs split them in-registers (same bytes moved).
// ---------------------------------------------------------------------------
__global__ __launch_bounds__(256) void prep_weights(
    const float* __restrict__ w2, const float* __restrict__ w3,
    short* __restrict__ Wf2h, short* __restrict__ Wf2l,
    short* __restrict__ Wq3h, short* __restrict__ Wq3l)
{
    const int N1 = 24576, N2 = 98304;
    int gid = blockIdx.x * 256 + threadIdx.x;
    if (gid >= N1 + N2) return;
    float v; short *ph, *pl; int o;
    if (gid < N1) {
        o = gid;
        int ii = o & 7, q = o >> 3;
        int lane = q & 63, q2 = q >> 6;
        int kf = q2 % 6, ctile = q2 / 6;
        int co = ctile * 16 + (lane & 15);
        int Kidx = kf * 32 + (lane >> 4) * 8 + ii;
        v = w2[(co * 64 + (Kidx & 63)) * 3 + (Kidx >> 6)];
        ph = Wf2h; pl = Wf2l;
    } else {
        o = gid - N1;
        int ii = o & 7, q = o >> 3;
        int lane = q & 63, q2 = q >> 6;
        int kstep = q2 % 24, ctile = q2 / 24;
        int co = ctile * 32 + (lane & 31);
        int Kidx = kstep * 16 + (lane >> 5) * 8 + ii;
        v = w3[(co * 128 + (Kidx & 127)) * 3 + (Kidx >> 7)];
        ph = Wq3h; pl = Wq3l;
    }
    unsigned short h = f2bf(v);
    ph[o] = (short)h;
    pl[o] = (short)f2bf(v - bf2f(h));
}

// ---------------------------------------------------------------------------
// Fused conv1(VALU fp32) + conv2 (16x16 MFMA) + conv3 (32x32 MFMA) + pools.
// 512 threads / 8 waves per block, one block per sequence. FROZEN at the
// best-measured r10/r13 configuration (64 VGPR + 64 AGPR = 128 regs/wave =
// exactly 4 waves/SIMD; register-limited, 2 blocks/CU).
// NOTE: do NOT raise the min-waves launch-bounds arg — (512,6) twice produced
// a 40-VGPR cap with total acc spill (0.44-0.88 GB/dispatch, 4.4x slower).
// ---------------------------------------------------------------------------
__global__ __launch_bounds__(512, 4) void conv_fused_mfma(
    const float* __restrict__ xg, const float* __restrict__ w1,
    const float* __restrict__ b1, const float* __restrict__ g1, const float* __restrict__ be1,
    const float* __restrict__ m1, const float* __restrict__ v1,
    const float* __restrict__ b2, const float* __restrict__ g2, const float* __restrict__ be2,
    const float* __restrict__ m2, const float* __restrict__ v2,
    const float* __restrict__ b3, const float* __restrict__ g3, const float* __restrict__ be3,
    const float* __restrict__ m3, const float* __restrict__ v3,
    const short* __restrict__ Wf2h, const short* __restrict__ Wf2l,
    const short* __restrict__ Wq3h, const short* __restrict__ Wq3l,
    short* __restrict__ ms)
{
    __shared__ float sx[6][130];                    // col t+1 holds time t
    __shared__ __align__(16) short h1s[130 * 64];   // [row=t+1][ci], swizzled
    __shared__ __align__(16) short h2s[130 * 128];  // [row=t+1][ci], swizzled

    const int tid = threadIdx.x;
    const int n = blockIdx.x;
    const int wv = tid >> 6, lane = tid & 63;
    const int l15 = lane & 15, lhi = lane >> 4;

    const float* xrow = xg + (size_t)n * 768;
    {
        int idx = tid;
        float vv = xrow[idx];
        int t = idx / 6, c = idx - t * 6;
        sx[c][t + 1] = vv;
        idx = tid + 512;
        if (idx < 768) {
            vv = xrow[idx];
            t = idx / 6; c = idx - t * 6;
            sx[c][t + 1] = vv;
        }
    }
    if (tid < 6)   { sx[tid][0] = 0.f; sx[tid][129] = 0.f; }
    if (tid < 64)  { h1s[tid] = 0; h1s[129 * 64 + tid] = 0; }
    if (tid < 128) { h2s[tid] = 0; h2s[129 * 128 + tid] = 0; }
    __syncthreads();

    // ---- conv1: 6 -> 64, fp32 VALU; thread = 4co x 4t (co across lanes) ----
    {
        const int t0 = (tid >> 4) * 4, co0 = (tid & 15) * 4;
        float a1v[4], c1v[4];
        #pragma unroll
        for (int c = 0; c < 4; ++c) {
            int co = co0 + c;
            float a = g1[co] * rsqrtf(v1[co] + 1e-5f);
            a1v[c] = a;
            c1v[c] = (b1[co] - m1[co]) * a + be1[co];
        }
        float acc[4][4];
        #pragma unroll
        for (int c = 0; c < 4; ++c)
            #pragma unroll
            for (int t = 0; t < 4; ++t) acc[c][t] = 0.f;
        #pragma unroll
        for (int ci = 0; ci < 6; ++ci) {
            float s[6];
            #pragma unroll
            for (int u = 0; u < 6; ++u) s[u] = sx[ci][t0 + u];
            #pragma unroll
            for (int c = 0; c < 4; ++c) {
                const float* wp = w1 + ((co0 + c) * 6 + ci) * 3;
                float wa = wp[0], wb = wp[1], wc = wp[2];
                #pragma unroll
                for (int t = 0; t < 4; ++t)
                    acc[c][t] = fmaf(wa, s[t], fmaf(wb, s[t + 1], fmaf(wc, s[t + 2], acc[c][t])));
            }
        }
        char* h1b = (char*)h1s;
        #pragma unroll
        for (int t = 0; t < 4; ++t) {
            short4v pk;
            #pragma unroll
            for (int c = 0; c < 4; ++c) {
                float v = fmaf(a1v[c], acc[c][t], c1v[c]);
                v = LRELU(v);
                pk[c] = (short)f2bf(v);
            }
            int row = t0 + t + 1;
            int byt = (row * 128 + co0 * 2) ^ ((row & 7) << 4);
            *(short4v*)(h1b + byt) = pk;
        }
    }
    __syncthreads();

    // ---- conv2: 64 -> 128 MFMA 16x16 (A=weights: D row=co, col=t) ----
    {
        f32x4 acc[8];
        #pragma unroll
        for (int j = 0; j < 8; ++j) acc[j] = (f32x4){0.f, 0.f, 0.f, 0.f};
        const char* h1b = (const char*)h1s;
        __builtin_amdgcn_s_setprio(1);
        for (int kf = 0; kf < 6; ++kf) {
            int k = kf >> 1, ci0 = (kf & 1) * 32;
            int colb = (ci0 + lhi * 8) * 2;
            size_t woff = ((size_t)(wv * 6 + kf) * 64 + lane) * 8;
            short8v ah = *(const short8v*)(Wf2h + woff);
            short8v al = *(const short8v*)(Wf2l + woff);
            #pragma unroll
            for (int j = 0; j < 8; ++j) {
                int row = j * 16 + l15 + k;
                short8v bfr = *(const short8v*)(h1b + ((row * 128 + colb) ^ ((row & 7) << 4)));
                acc[j] = MFMA16(ah, bfr, acc[j]);
                acc[j] = MFMA16(al, bfr, acc[j]);
            }
        }
        __builtin_amdgcn_s_setprio(0);
        char* h2b = (char*)h2s;
        {
            int cob = wv * 16 + lhi * 4;
            float a2v[4], c2v[4];
            #pragma unroll
            for (int c = 0; c < 4; ++c) {
                int co = cob + c;
                float a = g2[co] * rsqrtf(v2[co] + 1e-5f);
                a2v[c] = a;
                c2v[c] = (b2[co] - m2[co]) * a + be2[co];
            }
            #pragma unroll
            for (int j = 0; j < 8; ++j) {
                int t = j * 16 + l15;
                float v0 = fmaf(a2v[0], acc[j][0], c2v[0]); v0 = LRELU(v0);
                float v1_ = fmaf(a2v[1], acc[j][1], c2v[1]); v1_ = LRELU(v1_);
                float v2_ = fmaf(a2v[2], acc[j][2], c2v[2]); v2_ = LRELU(v2_);
                float v3_ = fmaf(a2v[3], acc[j][3], c2v[3]); v3_ = LRELU(v3_);
                short4v pk;
                pk[0] = (short)f2bf(v0); pk[1] = (short)f2bf(v1_);
                pk[2] = (short)f2bf(v2_); pk[3] = (short)f2bf(v3_);
                int row = t + 1;
                int byt = (row * 256 + cob * 2) ^ ((row & 7) << 4);
                *(short4v*)(h2b + byt) = pk;
            }
        }
    }
    __syncthreads();

    // ---- conv3: 128 -> 256 MFMA 32x32 swapped (A=acts: D col=co) + pools ----
    {
        const int l31 = lane & 31, lh = lane >> 5;
        f32x16 acc[4];
        #pragma unroll
        for (int tt = 0; tt < 4; ++tt)
            #pragma unroll
            for (int r = 0; r < 16; ++r) acc[tt][r] = 0.f;
        const char* h2b = (const char*)h2s;
        __builtin_amdgcn_s_setprio(1);
        for (int kstep = 0; kstep < 24; ++kstep) {
            int k = kstep >> 3;                         // conv tap 0..2
            int colb = (kstep & 7) * 32 + lh * 16;      // byte col of 8 ci
            size_t foff = ((size_t)(wv * 24 + kstep) * 64 + lane) * 8;
            short8v bh = *(const short8v*)(Wq3h + foff);
            short8v bl = *(const short8v*)(Wq3l + foff);
            #pragma unroll
            for (int tt = 0; tt < 4; ++tt) {
                int row = tt * 32 + l31 + k;
                short8v afr = *(const short8v*)(h2b + ((row * 256 + colb) ^ ((row & 7) << 4)));
                acc[tt] = MFMA32(afr, bh, acc[tt]);
                acc[tt] = MFMA32(afr, bl, acc[tt]);
            }
        }
        __builtin_amdgcn_s_setprio(0);
        short* msrow = ms + (size_t)n * 3328;
        int co = wv * 32 + l31;
        float a3v = g3[co] * rsqrtf(v3[co] + 1e-5f);
        float c3v = (b3[co] - m3[co]) * a3v + be3[co];
        float s16[8]; float h128 = 0.f;
        #pragma unroll
        for (int tt = 0; tt < 4; ++tt) {
            float b0 = 0.f, b1 = 0.f;
            #pragma unroll
            for (int r = 0; r < 8; ++r) {
                float v = fmaf(a3v, acc[tt][r], c3v);
                v = LRELU(v);
                b0 += v;
            }
            #pragma unroll
            for (int r = 8; r < 16; ++r) {
                float v = fmaf(a3v, acc[tt][r], c3v);
                v = LRELU(v);
                b1 += v;
            }
            b0 += __shfl_xor(b0, 32);
            b1 += __shfl_xor(b1, 32);
            s16[2 * tt] = b0; s16[2 * tt + 1] = b1;
            h128 += b0 + b1;
        }
        if (lane < 32) {
            short8v pk8;
            #pragma unroll
            for (int j = 0; j < 8; ++j) pk8[j] = (short)f2bf(s16[j] * (1.f / 16.f));
            *(short8v*)(msrow + co * 8) = pk8;
            short4v pk4;
            #pragma unroll
            for (int jj = 0; jj < 4; ++jj)
                pk4[jj] = (short)f2bf((s16[2 * jj] + s16[2 * jj + 1]) * (1.f / 32.f));
            *(short4v*)(msrow + 2048 + co * 4) = pk4;
            msrow[3072 + co] = (short)f2bf(h128 * (1.f / 128.f));
        }
    }
}

// ---------------------------------------------------------------------------
// gemm1 split-K: P[kk][1024][512] f32 partials, no bias/act.
// W is fp32, split hi/lo IN-KERNEL (same bytes as pre-split bf16 planes).
// 256 threads; block 64n x 64m, 4 waves of 32n x 32m, K chunk = 832.
// ---------------------------------------------------------------------------
__global__ __launch_bounds__(256) void gemm1_splitk(
    const float* __restrict__ W, const short* __restrict__ Act,
    float* __restrict__ P)
{
    const int K = 3328, KCHUNK = 832;
    const int tid = threadIdx.x;
    const int w = tid >> 6, lane = tid & 63;
    const int l15 = lane & 15, lhi = lane >> 4;
    const int n0 = blockIdx.x * 64 + (w & 1) * 32;
    const int m0 = blockIdx.y * 64 + (w >> 1) * 32;
    const int kbeg = blockIdx.z * KCHUNK;

    f32x4 acc[2][2];
    #pragma unroll
    for (int i = 0; i < 2; ++i)
        #pragma unroll
        for (int j = 0; j < 2; ++j) acc[i][j] = (f32x4){0.f, 0.f, 0.f, 0.f};

    const float* wp0 = W + (size_t)(n0 + l15) * K + kbeg + lhi * 8;
    const float* wp1 = wp0 + 16 * K;
    const short* bp0 = Act + (size_t)(m0 + l15) * K + kbeg + lhi * 8;
    const short* bp1 = bp0 + 16 * K;

    #pragma unroll 2
    for (int k0 = 0; k0 < KCHUNK; k0 += 32) {
        short8v b0 = *(const short8v*)(bp0 + k0);
        short8v b1 = *(const short8v*)(bp1 + k0);
        f32x8 w0 = *(const f32x8*)(wp0 + k0);
        f32x8 w1 = *(const f32x8*)(wp1 + k0);
        short8v a0h, a0l, a1h, a1l;
        split8(w0, a0h, a0l);
        split8(w1, a1h, a1l);
        acc[0][0] = MFMA16(a0h, b0, acc[0][0]); acc[0][0] = MFMA16(a0l, b0, acc[0][0]);
        acc[0][1] = MFMA16(a0h, b1, acc[0][1]); acc[0][1] = MFMA16(a0l, b1, acc[0][1]);
        acc[1][0] = MFMA16(a1h, b0, acc[1][0]); acc[1][0] = MFMA16(a1l, b0, acc[1][0]);
        acc[1][1] = MFMA16(a1h, b1, acc[1][1]); acc[1][1] = MFMA16(a1l, b1, acc[1][1]);
    }

    float* Pk = P + (size_t)blockIdx.z * (1024 * 512);
    #pragma unroll
    for (int ni = 0; ni < 2; ++ni) {
        int nb = n0 + ni * 16 + lhi * 4;
        #pragma unroll
        for (int mi = 0; mi < 2; ++mi) {
            int m = m0 + mi * 16 + l15;
            *(f32x4*)(Pk + (size_t)m * 512 + nb) = acc[ni][mi];
        }
    }
}

// Combine split-K partials: sum 4 planes + bias + relu -> bf16 h2l.
__global__ __launch_bounds__(256) void combine_h2(
    const float* __restrict__ P, const float* __restrict__ bias,
    short* __restrict__ h2l)
{
    int i4 = blockIdx.x * 256 + threadIdx.x;     // 0..131071, 4 floats each
    const f32x4* p = (const f32x4*)P;
    f32x4 s0 = p[i4], s1 = p[i4 + 131072], s2 = p[i4 + 262144], s3 = p[i4 + 393216];
    int nb = (i4 * 4) & 511;
    f32x4 b = *(const f32x4*)(bias + nb);
    float v0 = fmaxf(s0[0] + s1[0] + s2[0] + s3[0] + b[0], 0.f);
    float v1 = fmaxf(s0[1] + s1[1] + s2[1] + s3[1] + b[1], 0.f);
    float v2 = fmaxf(s0[2] + s1[2] + s2[2] + s3[2] + b[2], 0.f);
    float v3 = fmaxf(s0[3] + s1[3] + s2[3] + s3[3] + b[3], 0.f);
    uint2v pk;
    pk[0] = cvt_pk_bf16(v0, v1);
    pk[1] = cvt_pk_bf16(v2, v3);
    *(uint2v*)(h2l + (size_t)i4 * 4) = pk;
}

// ---------------------------------------------------------------------------
// gemm2: out[1024][256] f32 = h2l[1024][512] x lw2^T + lb2.
// W fp32, split in-kernel. Block 32n x 32m, 4 waves of 16n x 16m. 256 blocks.
// ---------------------------------------------------------------------------
__global__ __launch_bounds__(256) void gemm2_kernel(
    const float* __restrict__ W, const short* __restrict__ Act,
    const float* __restrict__ bias, float* __restrict__ out)
{
    const int K = 512;
    const int tid = threadIdx.x;
    const int w = tid >> 6, lane = tid & 63;
    const int l15 = lane & 15, lhi = lane >> 4;
    const int n0 = blockIdx.x * 32 + (w & 1) * 16;
    const int m0 = blockIdx.y * 32 + (w >> 1) * 16;

    f32x4 acc = (f32x4){0.f, 0.f, 0.f, 0.f};
    const float* wp = W + (size_t)(n0 + l15) * K + lhi * 8;
    const short* bp = Act + (size_t)(m0 + l15) * K + lhi * 8;

    #pragma unroll 4
    for (int k0 = 0; k0 < K; k0 += 32) {
        short8v b = *(const short8v*)(bp + k0);
        f32x8 wv8 = *(const f32x8*)(wp + k0);
        short8v ah, al;
        split8(wv8, ah, al);
        acc = MFMA16(ah, b, acc);
        acc = MFMA16(al, b, acc);
    }

    f32x4 bs = *(const f32x4*)(bias + n0 + lhi * 4);
    f32x4 vv;
    #pragma unroll
    for (int r = 0; r < 4; ++r) vv[r] = acc[r] + bs[r];
    *(f32x4*)(out + (size_t)(m0 + l15) * 256 + n0 + lhi * 4) = vv;
}

extern "C" void kernel_launch(void* const* d_in, const int* in_sizes, int n_in,
                              void* d_out, int out_size, void* d_ws, size_t ws_size,
                              hipStream_t stream) {
    int I_x, I_w1, I_b1, I_w2, I_b2, I_w3, I_b3;
    int I_g1, I_be1, I_m1, I_v1, I_g2, I_be2, I_m2, I_v2, I_g3, I_be3, I_m3, I_v3;
    int I_lw1, I_lb1, I_lw2, I_lb2;
    if (in_sizes[3] == 24576) {
        I_x=0; I_w1=1; I_b1=2; I_w2=3; I_b2=4; I_w3=5; I_b3=6;
        I_g1=7; I_be1=8; I_m1=9; I_v1=10; I_g2=11; I_be2=12; I_m2=13; I_v2=14;
        I_g3=15; I_be3=16; I_m3=17; I_v3=18; I_lw1=19; I_lb1=20; I_lw2=21; I_lb2=22;
    } else {
        I_x=0; I_w1=1; I_b1=2; I_g1=3; I_be1=4; I_m1=5; I_v1=6;
        I_w2=7; I_b2=8; I_g2=9; I_be2=10; I_m2=11; I_v2=12;
        I_w3=13; I_b3=14; I_g3=15; I_be3=16; I_m3=17; I_v3=18;
        I_lw1=19; I_lb1=20; I_lw2=21; I_lb2=22;
    }

    const float* x   = (const float*)d_in[I_x];
    const float* w1  = (const float*)d_in[I_w1];
    const float* b1  = (const float*)d_in[I_b1];
    const float* w2  = (const float*)d_in[I_w2];
    const float* b2  = (const float*)d_in[I_b2];
    const float* w3  = (const float*)d_in[I_w3];
    const float* b3  = (const float*)d_in[I_b3];
    const float* g1  = (const float*)d_in[I_g1];
    const float* be1 = (const float*)d_in[I_be1];
    const float* m1  = (const float*)d_in[I_m1];
    const float* v1  = (const float*)d_in[I_v1];
    const float* g2  = (const float*)d_in[I_g2];
    const float* be2 = (const float*)d_in[I_be2];
    const float* m2  = (const float*)d_in[I_m2];
    const float* v2  = (const float*)d_in[I_v2];
    const float* g3  = (const float*)d_in[I_g3];
    const float* be3 = (const float*)d_in[I_be3];
    const float* m3  = (const float*)d_in[I_m3];
    const float* v3  = (const float*)d_in[I_v3];
    const float* lw1 = (const float*)d_in[I_lw1];
    const float* lb1 = (const float*)d_in[I_lb1];
    const float* lw2 = (const float*)d_in[I_lw2];
    const float* lb2 = (const float*)d_in[I_lb2];

    char* wsb = (char*)d_ws;
    short* ms   = (short*)(wsb);                 // 1024*3328*2 = 6,815,744
    short* h2l  = (short*)(wsb + 6815744);       // 1024*512*2  = 1,048,576
    short* Wf2h = (short*)(wsb + 7864320);       // 24576*2 = 49,152
    short* Wf2l = (short*)(wsb + 7913472);
    short* Wq3h = (short*)(wsb + 7962624);       // 98304*2 = 196,608
    short* Wq3l = (short*)(wsb + 8159232);       // -> 8,355,840
    float* P    = (float*)(wsb + 8355840);       // 4*1024*512*4 = 8,388,608 -> 16,744,448

    prep_weights<<<480, 256, 0, stream>>>(w2, w3, Wf2h, Wf2l, Wq3h, Wq3l);

    conv_fused_mfma<<<1024, 512, 0, stream>>>(
        x, w1, b1, g1, be1, m1, v1, b2, g2, be2, m2, v2,
        b3, g3, be3, m3, v3, Wf2h, Wf2l, Wq3h, Wq3l, ms);

    gemm1_splitk<<<dim3(8, 16, 4), 256, 0, stream>>>(lw1, ms, P);
    combine_h2<<<512, 256, 0, stream>>>(P, lb1, h2l);
    gemm2_kernel<<<dim3(8, 32), 256, 0, stream>>>(lw2, h2l, lb2, (float*)d_out);
}

// Round 16
// 110.210 us; speedup vs baseline: 2.9068x; 1.0935x over previous
//
#include <hip/hip_runtime.h>
#include <hip/hip_bf16.h>

typedef __attribute__((ext_vector_type(8))) short short8v;
typedef __attribute__((ext_vector_type(4))) short short4v;
typedef __attribute__((ext_vector_type(4))) float f32x4;
typedef __attribute__((ext_vector_type(8))) float f32x8;
typedef __attribute__((ext_vector_type(16))) float f32x16;
typedef __attribute__((ext_vector_type(2))) unsigned int uint2v;
typedef __attribute__((ext_vector_type(4))) unsigned int uint4v;

#define LRELU(v) ((v) > 0.f ? (v) : 0.1f * (v))
#define MFMA16(a, b, c) __builtin_amdgcn_mfma_f32_16x16x32_bf16((a), (b), (c), 0, 0, 0)
#define MFMA32(a, b, c) __builtin_amdgcn_mfma_f32_32x32x16_bf16((a), (b), (c), 0, 0, 0)

__device__ inline unsigned short f2bf(float f) {
    unsigned u = __float_as_uint(f);
    u += 0x7FFF + ((u >> 16) & 1);          // RNE
    return (unsigned short)(u >> 16);
}
__device__ inline float bf2f(unsigned short h) {
    return __uint_as_float(((unsigned)h) << 16);
}
__device__ inline unsigned cvt_pk_bf16(float a, float b) {
    unsigned r;
    asm("v_cvt_pk_bf16_f32 %0, %1, %2" : "=v"(r) : "v"(a), "v"(b));
    return r;
}
// Split 8 fp32 into hi/lo bf16 planes in-registers (RNE, HW cvt_pk).
__device__ inline void split8(f32x8 v, short8v& hh, short8v& ll) {
    uint4v hu, lu;
    #pragma unroll
    for (int p = 0; p < 4; ++p) {
        float v0 = v[2 * p], v1 = v[2 * p + 1];
        unsigned hp = cvt_pk_bf16(v0, v1);
        float h0 = __uint_as_float(hp << 16);
        float h1 = __uint_as_float(hp & 0xFFFF0000u);
        unsigned lp = cvt_pk_bf16(v0 - h0, v1 - h1);
        hu[p] = hp; lu[p] = lp;
    }
    hh = __builtin_bit_cast(short8v, hu);
    ll = __builtin_bit_cast(short8v, lu);
}

// ---------------------------------------------------------------------------
// Prep: conv weights -> hi/lo bf16 fragments (123K elems, scalar);
//       lw1 -> SINGLE bf16 plane (3.4MB, float4-vectorized). The lo-plane of
//       lw1 contributes ~3e-3 to the output (activation rounding dominates),
//       so gemm1 runs single-plane: half the W traffic, half the MFMAs.
// ---------------------------------------------------------------------------
__global__ __launch_bounds__(256) void prep_weights(
    const float* __restrict__ w2, const float* __restrict__ w3,
    const float* __restrict__ lw1,
    short* __restrict__ Wf2h, short* __restrict__ Wf2l,
    short* __restrict__ Wq3h, short* __restrict__ Wq3l,
    short* __restrict__ lw1h)
{
    const int N1 = 24576, N2 = 98304;          // conv weight elems
    const int NV1 = 425984;                    // lw1 float4s
    int gid = blockIdx.x * 256 + threadIdx.x;  // grid 1024 -> 262144 threads

    if (gid < N1 + N2) {
        float v; short *ph, *pl; int o;
        if (gid < N1) {
            o = gid;
            int ii = o & 7, q = o >> 3;
            int lane = q & 63, q2 = q >> 6;
            int kf = q2 % 6, ctile = q2 / 6;
            int co = ctile * 16 + (lane & 15);
            int Kidx = kf * 32 + (lane >> 4) * 8 + ii;
            v = w2[(co * 64 + (Kidx & 63)) * 3 + (Kidx >> 6)];
            ph = Wf2h; pl = Wf2l;
        } else {
            o = gid - N1;
            int ii = o & 7, q = o >> 3;
            int lane = q & 63, q2 = q >> 6;
            int kstep = q2 % 24, ctile = q2 / 24;
            int co = ctile * 32 + (lane & 31);
            int Kidx = kstep * 16 + (lane >> 5) * 8 + ii;
            v = w3[(co * 128 + (Kidx & 127)) * 3 + (Kidx >> 7)];
            ph = Wq3h; pl = Wq3l;
        }
        unsigned short h = f2bf(v);
        ph[o] = (short)h;
        pl[o] = (short)f2bf(v - bf2f(h));
    }

    // lw1: vectorized single-plane bf16 cast
    for (int v4 = gid; v4 < NV1; v4 += 262144) {
        f32x4 f = ((const f32x4*)lw1)[v4];
        short4v h;
        #pragma unroll
        for (int c = 0; c < 4; ++c) h[c] = (short)f2bf(f[c]);
        ((short4v*)lw1h)[v4] = h;
    }
}

// ---------------------------------------------------------------------------
// Fused conv1(VALU fp32) + conv2 (16x16 MFMA) + conv3 (32x32 MFMA) + pools.
// 512 threads / 8 waves per block, one block per sequence. FROZEN at the
// best-measured r10/r13 configuration (64 VGPR + 64 AGPR = 128 regs/wave =
// exactly 4 waves/SIMD; register-limited, 2 blocks/CU).
// NOTE: do NOT raise the min-waves launch-bounds arg — (512,6) twice produced
// a 40-VGPR cap with total acc spill (0.44-0.88 GB/dispatch, 4.4x slower).
// ---------------------------------------------------------------------------
__global__ __launch_bounds__(512, 4) void conv_fused_mfma(
    const float* __restrict__ xg, const float* __restrict__ w1,
    const float* __restrict__ b1, const float* __restrict__ g1, const float* __restrict__ be1,
    const float* __restrict__ m1, const float* __restrict__ v1,
    const float* __restrict__ b2, const float* __restrict__ g2, const float* __restrict__ be2,
    const float* __restrict__ m2, const float* __restrict__ v2,
    const float* __restrict__ b3, const float* __restrict__ g3, const float* __restrict__ be3,
    const float* __restrict__ m3, const float* __restrict__ v3,
    const short* __restrict__ Wf2h, const short* __restrict__ Wf2l,
    const short* __restrict__ Wq3h, const short* __restrict__ Wq3l,
    short* __restrict__ ms)
{
    __shared__ float sx[6][130];                    // col t+1 holds time t
    __shared__ __align__(16) short h1s[130 * 64];   // [row=t+1][ci], swizzled
    __shared__ __align__(16) short h2s[130 * 128];  // [row=t+1][ci], swizzled

    const int tid = threadIdx.x;
    const int n = blockIdx.x;
    const int wv = tid >> 6, lane = tid & 63;
    const int l15 = lane & 15, lhi = lane >> 4;

    const float* xrow = xg + (size_t)n * 768;
    {
        int idx = tid;
        float vv = xrow[idx];
        int t = idx / 6, c = idx - t * 6;
        sx[c][t + 1] = vv;
        idx = tid + 512;
        if (idx < 768) {
            vv = xrow[idx];
            t = idx / 6; c = idx - t * 6;
            sx[c][t + 1] = vv;
        }
    }
    if (tid < 6)   { sx[tid][0] = 0.f; sx[tid][129] = 0.f; }
    if (tid < 64)  { h1s[tid] = 0; h1s[129 * 64 + tid] = 0; }
    if (tid < 128) { h2s[tid] = 0; h2s[129 * 128 + tid] = 0; }
    __syncthreads();

    // ---- conv1: 6 -> 64, fp32 VALU; thread = 4co x 4t (co across lanes) ----
    {
        const int t0 = (tid >> 4) * 4, co0 = (tid & 15) * 4;
        float a1v[4], c1v[4];
        #pragma unroll
        for (int c = 0; c < 4; ++c) {
            int co = co0 + c;
            float a = g1[co] * rsqrtf(v1[co] + 1e-5f);
            a1v[c] = a;
            c1v[c] = (b1[co] - m1[co]) * a + be1[co];
        }
        float acc[4][4];
        #pragma unroll
        for (int c = 0; c < 4; ++c)
            #pragma unroll
            for (int t = 0; t < 4; ++t) acc[c][t] = 0.f;
        #pragma unroll
        for (int ci = 0; ci < 6; ++ci) {
            float s[6];
            #pragma unroll
            for (int u = 0; u < 6; ++u) s[u] = sx[ci][t0 + u];
            #pragma unroll
            for (int c = 0; c < 4; ++c) {
                const float* wp = w1 + ((co0 + c) * 6 + ci) * 3;
                float wa = wp[0], wb = wp[1], wc = wp[2];
                #pragma unroll
                for (int t = 0; t < 4; ++t)
                    acc[c][t] = fmaf(wa, s[t], fmaf(wb, s[t + 1], fmaf(wc, s[t + 2], acc[c][t])));
            }
        }
        char* h1b = (char*)h1s;
        #pragma unroll
        for (int t = 0; t < 4; ++t) {
            short4v pk;
            #pragma unroll
            for (int c = 0; c < 4; ++c) {
                float v = fmaf(a1v[c], acc[c][t], c1v[c]);
                v = LRELU(v);
                pk[c] = (short)f2bf(v);
            }
            int row = t0 + t + 1;
            int byt = (row * 128 + co0 * 2) ^ ((row & 7) << 4);
            *(short4v*)(h1b + byt) = pk;
        }
    }
    __syncthreads();

    // ---- conv2: 64 -> 128 MFMA 16x16 (A=weights: D row=co, col=t) ----
    {
        f32x4 acc[8];
        #pragma unroll
        for (int j = 0; j < 8; ++j) acc[j] = (f32x4){0.f, 0.f, 0.f, 0.f};
        const char* h1b = (const char*)h1s;
        __builtin_amdgcn_s_setprio(1);
        for (int kf = 0; kf < 6; ++kf) {
            int k = kf >> 1, ci0 = (kf & 1) * 32;
            int colb = (ci0 + lhi * 8) * 2;
            size_t woff = ((size_t)(wv * 6 + kf) * 64 + lane) * 8;
            short8v ah = *(const short8v*)(Wf2h + woff);
            short8v al = *(const short8v*)(Wf2l + woff);
            #pragma unroll
            for (int j = 0; j < 8; ++j) {
                int row = j * 16 + l15 + k;
                short8v bfr = *(const short8v*)(h1b + ((row * 128 + colb) ^ ((row & 7) << 4)));
                acc[j] = MFMA16(ah, bfr, acc[j]);
                acc[j] = MFMA16(al, bfr, acc[j]);
            }
        }
        __builtin_amdgcn_s_setprio(0);
        char* h2b = (char*)h2s;
        {
            int cob = wv * 16 + lhi * 4;
            float a2v[4], c2v[4];
            #pragma unroll
            for (int c = 0; c < 4; ++c) {
                int co = cob + c;
                float a = g2[co] * rsqrtf(v2[co] + 1e-5f);
                a2v[c] = a;
                c2v[c] = (b2[co] - m2[co]) * a + be2[co];
            }
            #pragma unroll
            for (int j = 0; j < 8; ++j) {
                int t = j * 16 + l15;
                float v0 = fmaf(a2v[0], acc[j][0], c2v[0]); v0 = LRELU(v0);
                float v1_ = fmaf(a2v[1], acc[j][1], c2v[1]); v1_ = LRELU(v1_);
                float v2_ = fmaf(a2v[2], acc[j][2], c2v[2]); v2_ = LRELU(v2_);
                float v3_ = fmaf(a2v[3], acc[j][3], c2v[3]); v3_ = LRELU(v3_);
                short4v pk;
                pk[0] = (short)f2bf(v0); pk[1] = (short)f2bf(v1_);
                pk[2] = (short)f2bf(v2_); pk[3] = (short)f2bf(v3_);
                int row = t + 1;
                int byt = (row * 256 + cob * 2) ^ ((row & 7) << 4);
                *(short4v*)(h2b + byt) = pk;
            }
        }
    }
    __syncthreads();

    // ---- conv3: 128 -> 256 MFMA 32x32 swapped (A=acts: D col=co) + pools ----
    {
        const int l31 = lane & 31, lh = lane >> 5;
        f32x16 acc[4];
        #pragma unroll
        for (int tt = 0; tt < 4; ++tt)
            #pragma unroll
            for (int r = 0; r < 16; ++r) acc[tt][r] = 0.f;
        const char* h2b = (const char*)h2s;
        __builtin_amdgcn_s_setprio(1);
        for (int kstep = 0; kstep < 24; ++kstep) {
            int k = kstep >> 3;                         // conv tap 0..2
            int colb = (kstep & 7) * 32 + lh * 16;      // byte col of 8 ci
            size_t foff = ((size_t)(wv * 24 + kstep) * 64 + lane) * 8;
            short8v bh = *(const short8v*)(Wq3h + foff);
            short8v bl = *(const short8v*)(Wq3l + foff);
            #pragma unroll
            for (int tt = 0; tt < 4; ++tt) {
                int row = tt * 32 + l31 + k;
                short8v afr = *(const short8v*)(h2b + ((row * 256 + colb) ^ ((row & 7) << 4)));
                acc[tt] = MFMA32(afr, bh, acc[tt]);
                acc[tt] = MFMA32(afr, bl, acc[tt]);
            }
        }
        __builtin_amdgcn_s_setprio(0);
        short* msrow = ms + (size_t)n * 3328;
        int co = wv * 32 + l31;
        float a3v = g3[co] * rsqrtf(v3[co] + 1e-5f);
        float c3v = (b3[co] - m3[co]) * a3v + be3[co];
        float s16[8]; float h128 = 0.f;
        #pragma unroll
        for (int tt = 0; tt < 4; ++tt) {
            float b0 = 0.f, b1 = 0.f;
            #pragma unroll
            for (int r = 0; r < 8; ++r) {
                float v = fmaf(a3v, acc[tt][r], c3v);
                v = LRELU(v);
                b0 += v;
            }
            #pragma unroll
            for (int r = 8; r < 16; ++r) {
                float v = fmaf(a3v, acc[tt][r], c3v);
                v = LRELU(v);
                b1 += v;
            }
            b0 += __shfl_xor(b0, 32);
            b1 += __shfl_xor(b1, 32);
            s16[2 * tt] = b0; s16[2 * tt + 1] = b1;
            h128 += b0 + b1;
        }
        if (lane < 32) {
            short8v pk8;
            #pragma unroll
            for (int j = 0; j < 8; ++j) pk8[j] = (short)f2bf(s16[j] * (1.f / 16.f));
            *(short8v*)(msrow + co * 8) = pk8;
            short4v pk4;
            #pragma unroll
            for (int jj = 0; jj < 4; ++jj)
                pk4[jj] = (short)f2bf((s16[2 * jj] + s16[2 * jj + 1]) * (1.f / 32.f));
            *(short4v*)(msrow + 2048 + co * 4) = pk4;
            msrow[3072 + co] = (short)f2bf(h128 * (1.f / 128.f));
        }
    }
}

// ---------------------------------------------------------------------------
// gemm1 split-K: P[kk][1024][512] f32 partials, no bias/act.
// W is SINGLE-plane bf16 (half the traffic, half the MFMAs of hi/lo).
// 256 threads; block 64n x 64m, 4 waves of 32n x 32m, K chunk = 832.
// ---------------------------------------------------------------------------
__global__ __launch_bounds__(256) void gemm1_splitk(
    const short* __restrict__ Wh, const short* __restrict__ Act,
    float* __restrict__ P)
{
    const int K = 3328, KCHUNK = 832;
    const int tid = threadIdx.x;
    const int w = tid >> 6, lane = tid & 63;
    const int l15 = lane & 15, lhi = lane >> 4;
    const int n0 = blockIdx.x * 64 + (w & 1) * 32;
    const int m0 = blockIdx.y * 64 + (w >> 1) * 32;
    const int kbeg = blockIdx.z * KCHUNK;

    f32x4 acc[2][2];
    #pragma unroll
    for (int i = 0; i < 2; ++i)
        #pragma unroll
        for (int j = 0; j < 2; ++j) acc[i][j] = (f32x4){0.f, 0.f, 0.f, 0.f};

    const short* aw0 = Wh + (size_t)(n0 + l15) * K + kbeg + lhi * 8;
    const short* aw1 = aw0 + 16 * K;
    const short* bp0 = Act + (size_t)(m0 + l15) * K + kbeg + lhi * 8;
    const short* bp1 = bp0 + 16 * K;

    #pragma unroll 4
    for (int k0 = 0; k0 < KCHUNK; k0 += 32) {
        short8v b0 = *(const short8v*)(bp0 + k0);
        short8v b1 = *(const short8v*)(bp1 + k0);
        short8v a0 = *(const short8v*)(aw0 + k0);
        short8v a1 = *(const short8v*)(aw1 + k0);
        acc[0][0] = MFMA16(a0, b0, acc[0][0]);
        acc[0][1] = MFMA16(a0, b1, acc[0][1]);
        acc[1][0] = MFMA16(a1, b0, acc[1][0]);
        acc[1][1] = MFMA16(a1, b1, acc[1][1]);
    }

    float* Pk = P + (size_t)blockIdx.z * (1024 * 512);
    #pragma unroll
    for (int ni = 0; ni < 2; ++ni) {
        int nb = n0 + ni * 16 + lhi * 4;
        #pragma unroll
        for (int mi = 0; mi < 2; ++mi) {
            int m = m0 + mi * 16 + l15;
            *(f32x4*)(Pk + (size_t)m * 512 + nb) = acc[ni][mi];
        }
    }
}

// Combine split-K partials: sum 4 planes + bias + relu -> bf16 h2l.
__global__ __launch_bounds__(256) void combine_h2(
    const float* __restrict__ P, const float* __restrict__ bias,
    short* __restrict__ h2l)
{
    int i4 = blockIdx.x * 256 + threadIdx.x;     // 0..131071, 4 floats each
    const f32x4* p = (const f32x4*)P;
    f32x4 s0 = p[i4], s1 = p[i4 + 131072], s2 = p[i4 + 262144], s3 = p[i4 + 393216];
    int nb = (i4 * 4) & 511;
    f32x4 b = *(const f32x4*)(bias + nb);
    float v0 = fmaxf(s0[0] + s1[0] + s2[0] + s3[0] + b[0], 0.f);
    float v1 = fmaxf(s0[1] + s1[1] + s2[1] + s3[1] + b[1], 0.f);
    float v2 = fmaxf(s0[2] + s1[2] + s2[2] + s3[2] + b[2], 0.f);
    float v3 = fmaxf(s0[3] + s1[3] + s2[3] + s3[3] + b[3], 0.f);
    uint2v pk;
    pk[0] = cvt_pk_bf16(v0, v1);
    pk[1] = cvt_pk_bf16(v2, v3);
    *(uint2v*)(h2l + (size_t)i4 * 4) = pk;
}

// ---------------------------------------------------------------------------
// gemm2: out[1024][256] f32 = h2l[1024][512] x lw2^T + lb2.
// W fp32, split hi/lo in-kernel (final layer kept at full weight precision).
// ---------------------------------------------------------------------------
__global__ __launch_bounds__(256) void gemm2_kernel(
    const float* __restrict__ W, const short* __restrict__ Act,
    const float* __restrict__ bias, float* __restrict__ out)
{
    const int K = 512;
    const int tid = threadIdx.x;
    const int w = tid >> 6, lane = tid & 63;
    const int l15 = lane & 15, lhi = lane >> 4;
    const int n0 = blockIdx.x * 32 + (w & 1) * 16;
    const int m0 = blockIdx.y * 32 + (w >> 1) * 16;

    f32x4 acc = (f32x4){0.f, 0.f, 0.f, 0.f};
    const float* wp = W + (size_t)(n0 + l15) * K + lhi * 8;
    const short* bp = Act + (size_t)(m0 + l15) * K + lhi * 8;

    #pragma unroll 4
    for (int k0 = 0; k0 < K; k0 += 32) {
        short8v b = *(const short8v*)(bp + k0);
        f32x8 wv8 = *(const f32x8*)(wp + k0);
        short8v ah, al;
        split8(wv8, ah, al);
        acc = MFMA16(ah, b, acc);
        acc = MFMA16(al, b, acc);
    }

    f32x4 bs = *(const f32x4*)(bias + n0 + lhi * 4);
    f32x4 vv;
    #pragma unroll
    for (int r = 0; r < 4; ++r) vv[r] = acc[r] + bs[r];
    *(f32x4*)(out + (size_t)(m0 + l15) * 256 + n0 + lhi * 4) = vv;
}

extern "C" void kernel_launch(void* const* d_in, const int* in_sizes, int n_in,
                              void* d_out, int out_size, void* d_ws, size_t ws_size,
                              hipStream_t stream) {
    int I_x, I_w1, I_b1, I_w2, I_b2, I_w3, I_b3;
    int I_g1, I_be1, I_m1, I_v1, I_g2, I_be2, I_m2, I_v2, I_g3, I_be3, I_m3, I_v3;
    int I_lw1, I_lb1, I_lw2, I_lb2;
    if (in_sizes[3] == 24576) {
        I_x=0; I_w1=1; I_b1=2; I_w2=3; I_b2=4; I_w3=5; I_b3=6;
        I_g1=7; I_be1=8; I_m1=9; I_v1=10; I_g2=11; I_be2=12; I_m2=13; I_v2=14;
        I_g3=15; I_be3=16; I_m3=17; I_v3=18; I_lw1=19; I_lb1=20; I_lw2=21; I_lb2=22;
    } else {
        I_x=0; I_w1=1; I_b1=2; I_g1=3; I_be1=4; I_m1=5; I_v1=6;
        I_w2=7; I_b2=8; I_g2=9; I_be2=10; I_m2=11; I_v2=12;
        I_w3=13; I_b3=14; I_g3=15; I_be3=16; I_m3=17; I_v3=18;
        I_lw1=19; I_lb1=20; I_lw2=21; I_lb2=22;
    }

    const float* x   = (const float*)d_in[I_x];
    const float* w1  = (const float*)d_in[I_w1];
    const float* b1  = (const float*)d_in[I_b1];
    const float* w2  = (const float*)d_in[I_w2];
    const float* b2  = (const float*)d_in[I_b2];
    const float* w3  = (const float*)d_in[I_w3];
    const float* b3  = (const float*)d_in[I_b3];
    const float* g1  = (const float*)d_in[I_g1];
    const float* be1 = (const float*)d_in[I_be1];
    const float* m1  = (const float*)d_in[I_m1];
    const float* v1  = (const float*)d_in[I_v1];
    const float* g2  = (const float*)d_in[I_g2];
    const float* be2 = (const float*)d_in[I_be2];
    const float* m2  = (const float*)d_in[I_m2];
    const float* v2  = (const float*)d_in[I_v2];
    const float* g3  = (const float*)d_in[I_g3];
    const float* be3 = (const float*)d_in[I_be3];
    const float* m3  = (const float*)d_in[I_m3];
    const float* v3  = (const float*)d_in[I_v3];
    const float* lw1 = (const float*)d_in[I_lw1];
    const float* lb1 = (const float*)d_in[I_lb1];
    const float* lw2 = (const float*)d_in[I_lw2];
    const float* lb2 = (const float*)d_in[I_lb2];

    char* wsb = (char*)d_ws;
    short* ms   = (short*)(wsb);                 // 1024*3328*2 = 6,815,744
    short* h2l  = (short*)(wsb + 6815744);       // 1024*512*2  = 1,048,576
    short* Wf2h = (short*)(wsb + 7864320);       // 24576*2 = 49,152
    short* Wf2l = (short*)(wsb + 7913472);
    short* Wq3h = (short*)(wsb + 7962624);       // 98304*2 = 196,608
    short* Wq3l = (short*)(wsb + 8159232);       // -> 8,355,840
    short* lw1h = (short*)(wsb + 8355840);       // 1703936*2 = 3,407,872 -> 11,763,712
    float* P    = (float*)(wsb + 11763712);      // 4*1024*512*4 = 8,388,608 -> 20,152,320

    prep_weights<<<1024, 256, 0, stream>>>(w2, w3, lw1,
        Wf2h, Wf2l, Wq3h, Wq3l, lw1h);

    conv_fused_mfma<<<1024, 512, 0, stream>>>(
        x, w1, b1, g1, be1, m1, v1, b2, g2, be2, m2, v2,
        b3, g3, be3, m3, v3, Wf2h, Wf2l, Wq3h, Wq3l, ms);

    gemm1_splitk<<<dim3(8, 16, 4), 256, 0, stream>>>(lw1h, ms, P);
    combine_h2<<<512, 256, 0, stream>>>(P, lb1, h2l);
    gemm2_kernel<<<dim3(8, 32), 256, 0, stream>>>(lw2, h2l, lb2, (float*)d_out);
}

// Round 17
// 94.324 us; speedup vs baseline: 3.3964x; 1.1684x over previous
//
#include <hip/hip_runtime.h>
#include <hip/hip_bf16.h>

typedef __attribute__((ext_vector_type(8))) short short8v;
typedef __attribute__((ext_vector_type(4))) short short4v;
typedef __attribute__((ext_vector_type(4))) float f32x4;
typedef __attribute__((ext_vector_type(8))) float f32x8;
typedef __attribute__((ext_vector_type(16))) float f32x16;
typedef __attribute__((ext_vector_type(2))) unsigned int uint2v;
typedef __attribute__((ext_vector_type(4))) unsigned int uint4v;

#define LRELU(v) ((v) > 0.f ? (v) : 0.1f * (v))
#define MFMA16(a, b, c) __builtin_amdgcn_mfma_f32_16x16x32_bf16((a), (b), (c), 0, 0, 0)
#define MFMA32(a, b, c) __builtin_amdgcn_mfma_f32_32x32x16_bf16((a), (b), (c), 0, 0, 0)

__device__ inline unsigned short f2bf(float f) {
    unsigned u = __float_as_uint(f);
    u += 0x7FFF + ((u >> 16) & 1);          // RNE
    return (unsigned short)(u >> 16);
}
__device__ inline float bf2f(unsigned short h) {
    return __uint_as_float(((unsigned)h) << 16);
}
__device__ inline unsigned cvt_pk_bf16(float a, float b) {
    unsigned r;
    asm("v_cvt_pk_bf16_f32 %0, %1, %2" : "=v"(r) : "v"(a), "v"(b));
    return r;
}
// Split 8 fp32 into hi/lo bf16 planes in-registers (RNE, HW cvt_pk).
__device__ inline void split8(f32x8 v, short8v& hh, short8v& ll) {
    uint4v hu, lu;
    #pragma unroll
    for (int p = 0; p < 4; ++p) {
        float v0 = v[2 * p], v1 = v[2 * p + 1];
        unsigned hp = cvt_pk_bf16(v0, v1);
        float h0 = __uint_as_float(hp << 16);
        float h1 = __uint_as_float(hp & 0xFFFF0000u);
        unsigned lp = cvt_pk_bf16(v0 - h0, v1 - h1);
        hu[p] = hp; lu[p] = lp;
    }
    hh = __builtin_bit_cast(short8v, hu);
    ll = __builtin_bit_cast(short8v, lu);
}

// ---------------------------------------------------------------------------
// Prep: conv weights -> bf16 fragments. w2 keeps hi/lo; w3 hi-plane only
// (conv3 runs single-plane: its weight-rounding error is ~activation-level).
// lw1 -> single bf16 plane (proven +0.0078 absmax in r16, well in budget).
// ---------------------------------------------------------------------------
__global__ __launch_bounds__(256) void prep_weights(
    const float* __restrict__ w2, const float* __restrict__ w3,
    const float* __restrict__ lw1,
    short* __restrict__ Wf2h, short* __restrict__ Wf2l,
    short* __restrict__ Wq3h,
    short* __restrict__ lw1h)
{
    const int N1 = 24576, N2 = 98304;          // conv weight elems
    const int NV1 = 425984;                    // lw1 float4s
    int gid = blockIdx.x * 256 + threadIdx.x;  // grid 1024 -> 262144 threads

    if (gid < N1 + N2) {
        if (gid < N1) {
            int o = gid;
            int ii = o & 7, q = o >> 3;
            int lane = q & 63, q2 = q >> 6;
            int kf = q2 % 6, ctile = q2 / 6;
            int co = ctile * 16 + (lane & 15);
            int Kidx = kf * 32 + (lane >> 4) * 8 + ii;
            float v = w2[(co * 64 + (Kidx & 63)) * 3 + (Kidx >> 6)];
            unsigned short h = f2bf(v);
            Wf2h[o] = (short)h;
            Wf2l[o] = (short)f2bf(v - bf2f(h));
        } else {
            int o = gid - N1;
            int ii = o & 7, q = o >> 3;
            int lane = q & 63, q2 = q >> 6;
            int kstep = q2 % 24, ctile = q2 / 24;
            int co = ctile * 32 + (lane & 31);
            int Kidx = kstep * 16 + (lane >> 5) * 8 + ii;
            float v = w3[(co * 128 + (Kidx & 127)) * 3 + (Kidx >> 7)];
            Wq3h[o] = (short)f2bf(v);
        }
    }

    // lw1: vectorized single-plane bf16 cast
    for (int v4 = gid; v4 < NV1; v4 += 262144) {
        f32x4 f = ((const f32x4*)lw1)[v4];
        short4v h;
        #pragma unroll
        for (int c = 0; c < 4; ++c) h[c] = (short)f2bf(f[c]);
        ((short4v*)lw1h)[v4] = h;
    }
}

// ---------------------------------------------------------------------------
// Fused conv1(VALU fp32) + conv2 (16x16 MFMA hi/lo) + conv3 (32x32 MFMA,
// SINGLE-plane weights) + pools. 512 threads / 8 waves, one block/sequence.
// NOTE: do NOT raise the min-waves launch-bounds arg — (512,6) twice produced
// a 40-VGPR cap with total acc spill (0.44-0.88 GB/dispatch, 4.4x slower).
// ---------------------------------------------------------------------------
__global__ __launch_bounds__(512, 4) void conv_fused_mfma(
    const float* __restrict__ xg, const float* __restrict__ w1,
    const float* __restrict__ b1, const float* __restrict__ g1, const float* __restrict__ be1,
    const float* __restrict__ m1, const float* __restrict__ v1,
    const float* __restrict__ b2, const float* __restrict__ g2, const float* __restrict__ be2,
    const float* __restrict__ m2, const float* __restrict__ v2,
    const float* __restrict__ b3, const float* __restrict__ g3, const float* __restrict__ be3,
    const float* __restrict__ m3, const float* __restrict__ v3,
    const short* __restrict__ Wf2h, const short* __restrict__ Wf2l,
    const short* __restrict__ Wq3h,
    short* __restrict__ ms)
{
    __shared__ float sx[6][130];                    // col t+1 holds time t
    __shared__ __align__(16) short h1s[130 * 64];   // [row=t+1][ci], swizzled
    __shared__ __align__(16) short h2s[130 * 128];  // [row=t+1][ci], swizzled

    const int tid = threadIdx.x;
    const int n = blockIdx.x;
    const int wv = tid >> 6, lane = tid & 63;
    const int l15 = lane & 15, lhi = lane >> 4;

    const float* xrow = xg + (size_t)n * 768;
    {
        int idx = tid;
        float vv = xrow[idx];
        int t = idx / 6, c = idx - t * 6;
        sx[c][t + 1] = vv;
        idx = tid + 512;
        if (idx < 768) {
            vv = xrow[idx];
            t = idx / 6; c = idx - t * 6;
            sx[c][t + 1] = vv;
        }
    }
    if (tid < 6)   { sx[tid][0] = 0.f; sx[tid][129] = 0.f; }
    if (tid < 64)  { h1s[tid] = 0; h1s[129 * 64 + tid] = 0; }
    if (tid < 128) { h2s[tid] = 0; h2s[129 * 128 + tid] = 0; }
    __syncthreads();

    // ---- conv1: 6 -> 64, fp32 VALU; thread = 4co x 4t (co across lanes) ----
    {
        const int t0 = (tid >> 4) * 4, co0 = (tid & 15) * 4;
        float a1v[4], c1v[4];
        #pragma unroll
        for (int c = 0; c < 4; ++c) {
            int co = co0 + c;
            float a = g1[co] * rsqrtf(v1[co] + 1e-5f);
            a1v[c] = a;
            c1v[c] = (b1[co] - m1[co]) * a + be1[co];
        }
        float acc[4][4];
        #pragma unroll
        for (int c = 0; c < 4; ++c)
            #pragma unroll
            for (int t = 0; t < 4; ++t) acc[c][t] = 0.f;
        #pragma unroll
        for (int ci = 0; ci < 6; ++ci) {
            float s[6];
            #pragma unroll
            for (int u = 0; u < 6; ++u) s[u] = sx[ci][t0 + u];
            #pragma unroll
            for (int c = 0; c < 4; ++c) {
                const float* wp = w1 + ((co0 + c) * 6 + ci) * 3;
                float wa = wp[0], wb = wp[1], wc = wp[2];
                #pragma unroll
                for (int t = 0; t < 4; ++t)
                    acc[c][t] = fmaf(wa, s[t], fmaf(wb, s[t + 1], fmaf(wc, s[t + 2], acc[c][t])));
            }
        }
        char* h1b = (char*)h1s;
        #pragma unroll
        for (int t = 0; t < 4; ++t) {
            short4v pk;
            #pragma unroll
            for (int c = 0; c < 4; ++c) {
                float v = fmaf(a1v[c], acc[c][t], c1v[c]);
                v = LRELU(v);
                pk[c] = (short)f2bf(v);
            }
            int row = t0 + t + 1;
            int byt = (row * 128 + co0 * 2) ^ ((row & 7) << 4);
            *(short4v*)(h1b + byt) = pk;
        }
    }
    __syncthreads();

    // ---- conv2: 64 -> 128 MFMA 16x16 hi/lo (A=weights: D row=co, col=t) ----
    {
        f32x4 acc[8];
        #pragma unroll
        for (int j = 0; j < 8; ++j) acc[j] = (f32x4){0.f, 0.f, 0.f, 0.f};
        const char* h1b = (const char*)h1s;
        __builtin_amdgcn_s_setprio(1);
        for (int kf = 0; kf < 6; ++kf) {
            int k = kf >> 1, ci0 = (kf & 1) * 32;
            int colb = (ci0 + lhi * 8) * 2;
            size_t woff = ((size_t)(wv * 6 + kf) * 64 + lane) * 8;
            short8v ah = *(const short8v*)(Wf2h + woff);
            short8v al = *(const short8v*)(Wf2l + woff);
            #pragma unroll
            for (int j = 0; j < 8; ++j) {
                int row = j * 16 + l15 + k;
                short8v bfr = *(const short8v*)(h1b + ((row * 128 + colb) ^ ((row & 7) << 4)));
                acc[j] = MFMA16(ah, bfr, acc[j]);
                acc[j] = MFMA16(al, bfr, acc[j]);
            }
        }
        __builtin_amdgcn_s_setprio(0);
        char* h2b = (char*)h2s;
        {
            int cob = wv * 16 + lhi * 4;
            float a2v[4], c2v[4];
            #pragma unroll
            for (int c = 0; c < 4; ++c) {
                int co = cob + c;
                float a = g2[co] * rsqrtf(v2[co] + 1e-5f);
                a2v[c] = a;
                c2v[c] = (b2[co] - m2[co]) * a + be2[co];
            }
            #pragma unroll
            for (int j = 0; j < 8; ++j) {
                int t = j * 16 + l15;
                float v0 = fmaf(a2v[0], acc[j][0], c2v[0]); v0 = LRELU(v0);
                float v1_ = fmaf(a2v[1], acc[j][1], c2v[1]); v1_ = LRELU(v1_);
                float v2_ = fmaf(a2v[2], acc[j][2], c2v[2]); v2_ = LRELU(v2_);
                float v3_ = fmaf(a2v[3], acc[j][3], c2v[3]); v3_ = LRELU(v3_);
                short4v pk;
                pk[0] = (short)f2bf(v0); pk[1] = (short)f2bf(v1_);
                pk[2] = (short)f2bf(v2_); pk[3] = (short)f2bf(v3_);
                int row = t + 1;
                int byt = (row * 256 + cob * 2) ^ ((row & 7) << 4);
                *(short4v*)(h2b + byt) = pk;
            }
        }
    }
    __syncthreads();

    // ---- conv3: 128 -> 256 MFMA 32x32 SINGLE-plane (A=acts: D col=co) + pools
    {
        const int l31 = lane & 31, lh = lane >> 5;
        f32x16 acc[4];
        #pragma unroll
        for (int tt = 0; tt < 4; ++tt)
            #pragma unroll
            for (int r = 0; r < 16; ++r) acc[tt][r] = 0.f;
        const char* h2b = (const char*)h2s;
        __builtin_amdgcn_s_setprio(1);
        for (int kstep = 0; kstep < 24; ++kstep) {
            int k = kstep >> 3;                         // conv tap 0..2
            int colb = (kstep & 7) * 32 + lh * 16;      // byte col of 8 ci
            size_t foff = ((size_t)(wv * 24 + kstep) * 64 + lane) * 8;
            short8v bh = *(const short8v*)(Wq3h + foff);
            #pragma unroll
            for (int tt = 0; tt < 4; ++tt) {
                int row = tt * 32 + l31 + k;
                short8v afr = *(const short8v*)(h2b + ((row * 256 + colb) ^ ((row & 7) << 4)));
                acc[tt] = MFMA32(afr, bh, acc[tt]);
            }
        }
        __builtin_amdgcn_s_setprio(0);
        short* msrow = ms + (size_t)n * 3328;
        int co = wv * 32 + l31;
        float a3v = g3[co] * rsqrtf(v3[co] + 1e-5f);
        float c3v = (b3[co] - m3[co]) * a3v + be3[co];
        float s16[8]; float h128 = 0.f;
        #pragma unroll
        for (int tt = 0; tt < 4; ++tt) {
            float b0 = 0.f, b1 = 0.f;
            #pragma unroll
            for (int r = 0; r < 8; ++r) {
                float v = fmaf(a3v, acc[tt][r], c3v);
                v = LRELU(v);
                b0 += v;
            }
            #pragma unroll
            for (int r = 8; r < 16; ++r) {
                float v = fmaf(a3v, acc[tt][r], c3v);
                v = LRELU(v);
                b1 += v;
            }
            b0 += __shfl_xor(b0, 32);
            b1 += __shfl_xor(b1, 32);
            s16[2 * tt] = b0; s16[2 * tt + 1] = b1;
            h128 += b0 + b1;
        }
        if (lane < 32) {
            short8v pk8;
            #pragma unroll
            for (int j = 0; j < 8; ++j) pk8[j] = (short)f2bf(s16[j] * (1.f / 16.f));
            *(short8v*)(msrow + co * 8) = pk8;
            short4v pk4;
            #pragma unroll
            for (int jj = 0; jj < 4; ++jj)
                pk4[jj] = (short)f2bf((s16[2 * jj] + s16[2 * jj + 1]) * (1.f / 32.f));
            *(short4v*)(msrow + 2048 + co * 4) = pk4;
            msrow[3072 + co] = (short)f2bf(h128 * (1.f / 128.f));
        }
    }
}

// ---------------------------------------------------------------------------
// gemm1 split-K: P[kk][1024][512] f32 partials, no bias/act.
// W is SINGLE-plane bf16. 256 threads; block 64n x 64m, K chunk = 832.
// ---------------------------------------------------------------------------
__global__ __launch_bounds__(256) void gemm1_splitk(
    const short* __restrict__ Wh, const short* __restrict__ Act,
    float* __restrict__ P)
{
    const int K = 3328, KCHUNK = 832;
    const int tid = threadIdx.x;
    const int w = tid >> 6, lane = tid & 63;
    const int l15 = lane & 15, lhi = lane >> 4;
    const int n0 = blockIdx.x * 64 + (w & 1) * 32;
    const int m0 = blockIdx.y * 64 + (w >> 1) * 32;
    const int kbeg = blockIdx.z * KCHUNK;

    f32x4 acc[2][2];
    #pragma unroll
    for (int i = 0; i < 2; ++i)
        #pragma unroll
        for (int j = 0; j < 2; ++j) acc[i][j] = (f32x4){0.f, 0.f, 0.f, 0.f};

    const short* aw0 = Wh + (size_t)(n0 + l15) * K + kbeg + lhi * 8;
    const short* aw1 = aw0 + 16 * K;
    const short* bp0 = Act + (size_t)(m0 + l15) * K + kbeg + lhi * 8;
    const short* bp1 = bp0 + 16 * K;

    #pragma unroll 4
    for (int k0 = 0; k0 < KCHUNK; k0 += 32) {
        short8v b0 = *(const short8v*)(bp0 + k0);
        short8v b1 = *(const short8v*)(bp1 + k0);
        short8v a0 = *(const short8v*)(aw0 + k0);
        short8v a1 = *(const short8v*)(aw1 + k0);
        acc[0][0] = MFMA16(a0, b0, acc[0][0]);
        acc[0][1] = MFMA16(a0, b1, acc[0][1]);
        acc[1][0] = MFMA16(a1, b0, acc[1][0]);
        acc[1][1] = MFMA16(a1, b1, acc[1][1]);
    }

    float* Pk = P + (size_t)blockIdx.z * (1024 * 512);
    #pragma unroll
    for (int ni = 0; ni < 2; ++ni) {
        int nb = n0 + ni * 16 + lhi * 4;
        #pragma unroll
        for (int mi = 0; mi < 2; ++mi) {
            int m = m0 + mi * 16 + l15;
            *(f32x4*)(Pk + (size_t)m * 512 + nb) = acc[ni][mi];
        }
    }
}

// Combine split-K partials: sum 4 planes + bias + relu -> bf16 h2l.
__global__ __launch_bounds__(256) void combine_h2(
    const float* __restrict__ P, const float* __restrict__ bias,
    short* __restrict__ h2l)
{
    int i4 = blockIdx.x * 256 + threadIdx.x;     // 0..131071, 4 floats each
    const f32x4* p = (const f32x4*)P;
    f32x4 s0 = p[i4], s1 = p[i4 + 131072], s2 = p[i4 + 262144], s3 = p[i4 + 393216];
    int nb = (i4 * 4) & 511;
    f32x4 b = *(const f32x4*)(bias + nb);
    float v0 = fmaxf(s0[0] + s1[0] + s2[0] + s3[0] + b[0], 0.f);
    float v1 = fmaxf(s0[1] + s1[1] + s2[1] + s3[1] + b[1], 0.f);
    float v2 = fmaxf(s0[2] + s1[2] + s2[2] + s3[2] + b[2], 0.f);
    float v3 = fmaxf(s0[3] + s1[3] + s2[3] + s3[3] + b[3], 0.f);
    uint2v pk;
    pk[0] = cvt_pk_bf16(v0, v1);
    pk[1] = cvt_pk_bf16(v2, v3);
    *(uint2v*)(h2l + (size_t)i4 * 4) = pk;
}

// ---------------------------------------------------------------------------
// gemm2: out[1024][256] f32 = h2l[1024][512] x lw2^T + lb2.
// W fp32, split hi/lo in-kernel (final layer kept at full weight precision).
// ---------------------------------------------------------------------------
__global__ __launch_bounds__(256) void gemm2_kernel(
    const float* __restrict__ W, const short* __restrict__ Act,
    const float* __restrict__ bias, float* __restrict__ out)
{
    const int K = 512;
    const int tid = threadIdx.x;
    const int w = tid >> 6, lane = tid & 63;
    const int l15 = lane & 15, lhi = lane >> 4;
    const int n0 = blockIdx.x * 32 + (w & 1) * 16;
    const int m0 = blockIdx.y * 32 + (w >> 1) * 16;

    f32x4 acc = (f32x4){0.f, 0.f, 0.f, 0.f};
    const float* wp = W + (size_t)(n0 + l15) * K + lhi * 8;
    const short* bp = Act + (size_t)(m0 + l15) * K + lhi * 8;

    #pragma unroll 4
    for (int k0 = 0; k0 < K; k0 += 32) {
        short8v b = *(const short8v*)(bp + k0);
        f32x8 wv8 = *(const f32x8*)(wp + k0);
        short8v ah, al;
        split8(wv8, ah, al);
        acc = MFMA16(ah, b, acc);
        acc = MFMA16(al, b, acc);
    }

    f32x4 bs = *(const f32x4*)(bias + n0 + lhi * 4);
    f32x4 vv;
    #pragma unroll
    for (int r = 0; r < 4; ++r) vv[r] = acc[r] + bs[r];
    *(f32x4*)(out + (size_t)(m0 + l15) * 256 + n0 + lhi * 4) = vv;
}

extern "C" void kernel_launch(void* const* d_in, const int* in_sizes, int n_in,
                              void* d_out, int out_size, void* d_ws, size_t ws_size,
                              hipStream_t stream) {
    int I_x, I_w1, I_b1, I_w2, I_b2, I_w3, I_b3;
    int I_g1, I_be1, I_m1, I_v1, I_g2, I_be2, I_m2, I_v2, I_g3, I_be3, I_m3, I_v3;
    int I_lw1, I_lb1, I_lw2, I_lb2;
    if (in_sizes[3] == 24576) {
        I_x=0; I_w1=1; I_b1=2; I_w2=3; I_b2=4; I_w3=5; I_b3=6;
        I_g1=7; I_be1=8; I_m1=9; I_v1=10; I_g2=11; I_be2=12; I_m2=13; I_v2=14;
        I_g3=15; I_be3=16; I_m3=17; I_v3=18; I_lw1=19; I_lb1=20; I_lw2=21; I_lb2=22;
    } else {
        I_x=0; I_w1=1; I_b1=2; I_g1=3; I_be1=4; I_m1=5; I_v1=6;
        I_w2=7; I_b2=8; I_g2=9; I_be2=10; I_m2=11; I_v2=12;
        I_w3=13; I_b3=14; I_g3=15; I_be3=16; I_m3=17; I_v3=18;
        I_lw1=19; I_lb1=20; I_lw2=21; I_lb2=22;
    }

    const float* x   = (const float*)d_in[I_x];
    const float* w1  = (const float*)d_in[I_w1];
    const float* b1  = (const float*)d_in[I_b1];
    const float* w2  = (const float*)d_in[I_w2];
    const float* b2  = (const float*)d_in[I_b2];
    const float* w3  = (const float*)d_in[I_w3];
    const float* b3  = (const float*)d_in[I_b3];
    const float* g1  = (const float*)d_in[I_g1];
    const float* be1 = (const float*)d_in[I_be1];
    const float* m1  = (const float*)d_in[I_m1];
    const float* v1  = (const float*)d_in[I_v1];
    const float* g2  = (const float*)d_in[I_g2];
    const float* be2 = (const float*)d_in[I_be2];
    const float* m2  = (const float*)d_in[I_m2];
    const float* v2  = (const float*)d_in[I_v2];
    const float* g3  = (const float*)d_in[I_g3];
    const float* be3 = (const float*)d_in[I_be3];
    const float* m3  = (const float*)d_in[I_m3];
    const float* v3  = (const float*)d_in[I_v3];
    const float* lw1 = (const float*)d_in[I_lw1];
    const float* lb1 = (const float*)d_in[I_lb1];
    const float* lw2 = (const float*)d_in[I_lw2];
    const float* lb2 = (const float*)d_in[I_lb2];

    char* wsb = (char*)d_ws;
    short* ms   = (short*)(wsb);                 // 1024*3328*2 = 6,815,744
    short* h2l  = (short*)(wsb + 6815744);       // 1024*512*2  = 1,048,576
    short* Wf2h = (short*)(wsb + 7864320);       // 24576*2 = 49,152
    short* Wf2l = (short*)(wsb + 7913472);
    short* Wq3h = (short*)(wsb + 7962624);       // 98304*2 = 196,608 -> 8,159,232
    short* lw1h = (short*)(wsb + 8159232);       // 1703936*2 = 3,407,872 -> 11,567,104
    float* P    = (float*)(wsb + 11567104);      // 4*1024*512*4 = 8,388,608 -> 19,955,712

    prep_weights<<<1024, 256, 0, stream>>>(w2, w3, lw1,
        Wf2h, Wf2l, Wq3h, lw1h);

    conv_fused_mfma<<<1024, 512, 0, stream>>>(
        x, w1, b1, g1, be1, m1, v1, b2, g2, be2, m2, v2,
        b3, g3, be3, m3, v3, Wf2h, Wf2l, Wq3h, ms);

    gemm1_splitk<<<dim3(8, 16, 4), 256, 0, stream>>>(lw1h, ms, P);
    combine_h2<<<512, 256, 0, stream>>>(P, lb1, h2l);
    gemm2_kernel<<<dim3(8, 32), 256, 0, stream>>>(lw2, h2l, lb2, (float*)d_out);
}